// Round 5
// baseline (385.954 us; speedup 1.0000x reference)
//
#include <hip/hip_runtime.h>

#define N_NODES 100000
#define N_EDGES 1600000
#define C 128
#define LEAKY 0.01f
#define BN_EPS 1e-5f
#define NB1 391            // ceil(N_NODES/256)
#define PAD 16             // one counter per 64B line

typedef __attribute__((ext_vector_type(8))) short short8;   // 8 bf16 = 16B
typedef __attribute__((ext_vector_type(4))) float f32x4;

__device__ __forceinline__ unsigned short f2bf(float f) {   // RNE float->bf16
    unsigned int u = __builtin_bit_cast(unsigned int, f);
    u += 0x7FFFu + ((u >> 16) & 1u);
    return (unsigned short)(u >> 16);
}
__device__ __forceinline__ float bf2f(unsigned short b) {
    unsigned int u = ((unsigned int)b) << 16;
    return __builtin_bit_cast(float, u);
}

// ---------------------------------------------------------------- init: zero padded counters, stats; cast-transpose W
__global__ __launch_bounds__(256) void k_init(int* __restrict__ cnt,
                                              float* __restrict__ sums,
                                              float* __restrict__ sumsq,
                                              const float* __restrict__ W,
                                              unsigned short* __restrict__ wt) {
    int i = blockIdx.x * 256 + threadIdx.x;
    if (i < N_NODES * PAD / 4) ((int4*)cnt)[i] = make_int4(0, 0, 0, 0);
    if (i < C) { sums[i] = 0.0f; sumsq[i] = 0.0f; }
    if (i < C * C) wt[i] = f2bf(W[(i & 127) * C + (i >> 7)]);   // wt[c][k] = W[k][c]
}

// ---------------------------------------------------------------- in-degree count, 4 edges/thread, padded atomics
__global__ __launch_bounds__(256) void k_count(const int* __restrict__ dst,
                                               int* __restrict__ cnt) {
    int e0 = (blockIdx.x * 256 + threadIdx.x) * 4;
    if (e0 + 4 <= N_EDGES) {
        int4 d = *(const int4*)&dst[e0];
        atomicAdd(&cnt[d.x * PAD], 1);
        atomicAdd(&cnt[d.y * PAD], 1);
        atomicAdd(&cnt[d.z * PAD], 1);
        atomicAdd(&cnt[d.w * PAD], 1);
    } else {
        for (int e = e0; e < N_EDGES; ++e) atomicAdd(&cnt[dst[e] * PAD], 1);
    }
}

// ---------------------------------------------------------------- scan pass 1 (+ dinv = rsqrt(deg+1))
__global__ __launch_bounds__(256) void k_scan1(const int* __restrict__ cnt,
                                               int* __restrict__ offs,
                                               int* __restrict__ bsum,
                                               float* __restrict__ dinv) {
    __shared__ int tmp[256];
    int i = blockIdx.x * 256 + threadIdx.x;
    int v = (i < N_NODES) ? cnt[i * PAD] : 0;
    if (i < N_NODES) dinv[i] = rsqrtf((float)(v + 1));
    tmp[threadIdx.x] = v;
    __syncthreads();
    for (int off = 1; off < 256; off <<= 1) {
        int t = (threadIdx.x >= off) ? tmp[threadIdx.x - off] : 0;
        __syncthreads();
        tmp[threadIdx.x] += t;
        __syncthreads();
    }
    if (i < N_NODES) offs[i] = tmp[threadIdx.x] - v;
    if (threadIdx.x == 255) bsum[blockIdx.x] = tmp[255];
}

// ---------------------------------------------------------------- scan pass 2
__global__ __launch_bounds__(512) void k_scan2(int* __restrict__ bsum) {
    __shared__ int tmp[512];
    int v = (threadIdx.x < NB1) ? bsum[threadIdx.x] : 0;
    tmp[threadIdx.x] = v;
    __syncthreads();
    for (int off = 1; off < 512; off <<= 1) {
        int t = (threadIdx.x >= off) ? tmp[threadIdx.x - off] : 0;
        __syncthreads();
        tmp[threadIdx.x] += t;
        __syncthreads();
    }
    if (threadIdx.x < NB1) bsum[threadIdx.x] = tmp[threadIdx.x] - v;
}

// ---------------------------------------------------------------- scan pass 3 (+ sentinel)
__global__ __launch_bounds__(256) void k_scan3(int* __restrict__ offs,
                                               const int* __restrict__ bsum) {
    int i = blockIdx.x * 256 + threadIdx.x;
    if (i < N_NODES) offs[i] += bsum[blockIdx.x];
    if (i == 0) offs[N_NODES] = N_EDGES;
}

// ---------------------------------------------------------------- bucket fill: reverse-fill via atomicSub on counts
__global__ __launch_bounds__(256) void k_fill(const int* __restrict__ src,
                                              const int* __restrict__ dst,
                                              const int* __restrict__ offs,
                                              int* __restrict__ cnt,
                                              int* __restrict__ srt) {
    int e0 = (blockIdx.x * 256 + threadIdx.x) * 4;
    if (e0 + 4 <= N_EDGES) {
        int4 d = *(const int4*)&dst[e0];
        int4 s = *(const int4*)&src[e0];
        int ox = offs[d.x], oy = offs[d.y], oz = offs[d.z], ow = offs[d.w];
        int cx = atomicAdd(&cnt[d.x * PAD], -1);
        int cy = atomicAdd(&cnt[d.y * PAD], -1);
        int cz = atomicAdd(&cnt[d.z * PAD], -1);
        int cw = atomicAdd(&cnt[d.w * PAD], -1);
        srt[ox + cx - 1] = s.x;
        srt[oy + cy - 1] = s.y;
        srt[oz + cz - 1] = s.z;
        srt[ow + cw - 1] = s.w;
    } else {
        for (int e = e0; e < N_EDGES; ++e) {
            int d = dst[e];
            int o = atomicAdd(&cnt[d * PAD], -1);
            srt[offs[d] + o - 1] = src[e];
        }
    }
}

// ---------------------------------------------------------------- hs = (x @ W) * dinv[row], bf16 MFMA, fused cast
__global__ __launch_bounds__(256) void k_gemm(const float* __restrict__ x,
                                              const unsigned short* __restrict__ wt,
                                              const float* __restrict__ dinv,
                                              unsigned short* __restrict__ hs) {
    int tile = blockIdx.x * 4 + (threadIdx.x >> 6);
    if (tile >= N_NODES / 16) return;
    int lane = threadIdx.x & 63;
    int row0 = tile * 16;

    int ar = lane & 15;
    int kg = (lane >> 4) * 8;

    short8 a[4];
    #pragma unroll
    for (int kk = 0; kk < 4; ++kk) {
        const float* p = &x[(size_t)(row0 + ar) * C + kk * 32 + kg];
        float4 p0 = *(const float4*)p;
        float4 p1 = *(const float4*)(p + 4);
        short8 av;
        av[0] = (short)f2bf(p0.x); av[1] = (short)f2bf(p0.y);
        av[2] = (short)f2bf(p0.z); av[3] = (short)f2bf(p0.w);
        av[4] = (short)f2bf(p1.x); av[5] = (short)f2bf(p1.y);
        av[6] = (short)f2bf(p1.z); av[7] = (short)f2bf(p1.w);
        a[kk] = av;
    }

    int rb = (lane >> 4) * 4;
    float dv[4];
    #pragma unroll
    for (int r = 0; r < 4; ++r) dv[r] = dinv[row0 + rb + r];

    #pragma unroll
    for (int ct = 0; ct < 8; ++ct) {
        f32x4 acc = {0.f, 0.f, 0.f, 0.f};
        #pragma unroll
        for (int kk = 0; kk < 4; ++kk) {
            short8 b = *(const short8*)&wt[(size_t)(ct * 16 + ar) * C + kk * 32 + kg];
            acc = __builtin_amdgcn_mfma_f32_16x16x32_bf16(a[kk], b, acc, 0, 0, 0);
        }
        int col = ct * 16 + ar;
        #pragma unroll
        for (int r = 0; r < 4; ++r)
            hs[(size_t)(row0 + rb + r) * C + col] = f2bf(acc[r] * dv[r]);
    }
}

// ---------------------------------------------------------------- CSR aggregate: 32 lanes/node, 8-wide MLP gathers
__global__ __launch_bounds__(256) void k_aggregate(const ushort4* __restrict__ h4,
                                                   const int* __restrict__ srt,
                                                   const int* __restrict__ offs,
                                                   const float* __restrict__ dinv,
                                                   const float* __restrict__ bias,
                                                   float* __restrict__ out) {
    int node = blockIdx.x * 8 + (threadIdx.x >> 5);
    int lane = threadIdx.x & 31;

    float dn = dinv[node];
    int beg = offs[node];
    int end = offs[node + 1];

    ushort4 ms = h4[(size_t)node * 32 + lane];
    float ax = bf2f(ms.x), ay = bf2f(ms.y), az = bf2f(ms.z), aw = bf2f(ms.w);

    for (int k = beg; k < end; k += 8) {
        int   idx[8];
        float msk[8];
        #pragma unroll
        for (int i = 0; i < 8; ++i) {
            int ki = k + i;
            msk[i] = (ki < end) ? 1.0f : 0.0f;
            idx[i] = srt[(ki < end) ? ki : end - 1];
        }
        ushort4 m[8];
        #pragma unroll
        for (int i = 0; i < 8; ++i) m[i] = h4[(size_t)idx[i] * 32 + lane];
        #pragma unroll
        for (int i = 0; i < 8; ++i) {
            ax += msk[i] * bf2f(m[i].x);
            ay += msk[i] * bf2f(m[i].y);
            az += msk[i] * bf2f(m[i].z);
            aw += msk[i] * bf2f(m[i].w);
        }
    }

    float4 b = ((const float4*)bias)[lane];
    float4 v;
    v.x = dn * ax + b.x;
    v.y = dn * ay + b.y;
    v.z = dn * az + b.z;
    v.w = dn * aw + b.w;
    v.x = v.x > 0.f ? v.x : LEAKY * v.x;
    v.y = v.y > 0.f ? v.y : LEAKY * v.y;
    v.z = v.z > 0.f ? v.z : LEAKY * v.z;
    v.w = v.w > 0.f ? v.w : LEAKY * v.w;
    ((float4*)out)[(size_t)node * 32 + lane] = v;
}

// ---------------------------------------------------------------- BN stats
__global__ __launch_bounds__(256) void k_stats(const float* __restrict__ out,
                                               float* __restrict__ sums,
                                               float* __restrict__ sumsq) {
    int c = threadIdx.x & 127;
    int half = threadIdx.x >> 7;
    int base = blockIdx.x * 256;
    float s = 0.0f, q = 0.0f;
    for (int r = half; r < 256; r += 2) {
        int n = base + r;
        if (n >= N_NODES) break;
        float v = out[(size_t)n * C + c];
        s += v; q += v * v;
    }
    __shared__ float ls[256], lq[256];
    ls[threadIdx.x] = s; lq[threadIdx.x] = q;
    __syncthreads();
    if (threadIdx.x < 128) {
        atomicAdd(&sums[c],  ls[threadIdx.x] + ls[threadIdx.x + 128]);
        atomicAdd(&sumsq[c], lq[threadIdx.x] + lq[threadIdx.x + 128]);
    }
}

// ---------------------------------------------------------------- fold BN params
__global__ void k_params(const float* __restrict__ sums, const float* __restrict__ sumsq,
                         const float* __restrict__ gamma, const float* __restrict__ beta,
                         float* __restrict__ scale, float* __restrict__ shift) {
    int c = threadIdx.x;
    float inv_n = 1.0f / (float)N_NODES;
    float mean = sums[c] * inv_n;
    float var = sumsq[c] * inv_n - mean * mean;
    float sc = gamma[c] * rsqrtf(var + BN_EPS);
    scale[c] = sc;
    shift[c] = beta[c] - mean * sc;
}

// ---------------------------------------------------------------- apply
__global__ __launch_bounds__(256) void k_apply(float* __restrict__ out,
                                               const float* __restrict__ scale,
                                               const float* __restrict__ shift) {
    int i = blockIdx.x * 256 + threadIdx.x;
    int c4 = i & 31;
    float4 v = ((float4*)out)[i];
    float4 sc = ((const float4*)scale)[c4];
    float4 sh = ((const float4*)shift)[c4];
    v.x = v.x * sc.x + sh.x;
    v.y = v.y * sc.y + sh.y;
    v.z = v.z * sc.z + sh.z;
    v.w = v.w * sc.w + sh.w;
    ((float4*)out)[i] = v;
}

extern "C" void kernel_launch(void* const* d_in, const int* in_sizes, int n_in,
                              void* d_out, int out_size, void* d_ws, size_t ws_size,
                              hipStream_t stream) {
    const float* x     = (const float*)d_in[0];
    const int*   edge  = (const int*)d_in[1];
    const float* W     = (const float*)d_in[2];
    const float* bias  = (const float*)d_in[3];
    const float* gamma = (const float*)d_in[4];
    const float* beta  = (const float*)d_in[5];
    float* out = (float*)d_out;
    char* ws = (char*)d_ws;

    // workspace layout (~39.3 MB)
    unsigned short* hs  = (unsigned short*)ws;  ws += (size_t)N_NODES * C * 2;   // 25.6 MB
    unsigned short* wt  = (unsigned short*)ws;  ws += (size_t)C * C * 2;         // 32 KB
    int*   srt    = (int*)ws;                   ws += (size_t)N_EDGES * 4;       // 6.4 MB
    int*   cnt    = (int*)ws;                   ws += (size_t)N_NODES * PAD * 4; // 6.4 MB padded
    int*   offs   = (int*)ws;                   ws += (size_t)(N_NODES + 1) * 4;
    int*   bsum   = (int*)ws;                   ws += 512 * 4;
    float* dinv   = (float*)ws;                 ws += (size_t)N_NODES * 4;
    float* sums   = (float*)ws;                 ws += C * 4;
    float* sumsq  = (float*)ws;                 ws += C * 4;
    float* scale  = (float*)ws;                 ws += C * 4;
    float* shift  = (float*)ws;

    const int* src = edge;
    const int* dst = edge + N_EDGES;

    int nb_edge4 = (N_EDGES / 4 + 255) / 256;           // 1563
    k_init     <<<(N_NODES * PAD / 4 + 255) / 256, 256, 0, stream>>>(cnt, sums, sumsq, W, wt);
    k_count    <<<nb_edge4,              256, 0, stream>>>(dst, cnt);
    k_scan1    <<<NB1,                   256, 0, stream>>>(cnt, offs, bsum, dinv);
    k_scan2    <<<1,                     512, 0, stream>>>(bsum);
    k_scan3    <<<NB1,                   256, 0, stream>>>(offs, bsum);
    k_fill     <<<nb_edge4,              256, 0, stream>>>(src, dst, offs, cnt, srt);
    k_gemm     <<<(N_NODES / 16 + 3) / 4, 256, 0, stream>>>(x, wt, dinv, hs);
    k_aggregate<<<N_NODES / 8,           256, 0, stream>>>((const ushort4*)hs, srt, offs, dinv, bias, out);
    k_stats    <<<NB1,                   256, 0, stream>>>(out, sums, sumsq);
    k_params   <<<1, 128,                     0, stream>>>(sums, sumsq, gamma, beta, scale, shift);
    k_apply    <<<N_NODES * C / 4 / 256, 256, 0, stream>>>(out, scale, shift);
}

// Round 6
// 267.081 us; speedup vs baseline: 1.4451x; 1.4451x over previous
//
#include <hip/hip_runtime.h>

#define N_NODES 100000
#define N_EDGES 1600000
#define C 128
#define LEAKY 0.01f
#define BN_EPS 1e-5f
#define NB1 391            // ceil(N_NODES/256)
#define PAD 16             // one counter per 64B line

typedef __attribute__((ext_vector_type(8))) short short8;   // 8 bf16 = 16B
typedef __attribute__((ext_vector_type(4))) float f32x4;

__device__ __forceinline__ unsigned short f2bf(float f) {   // RNE float->bf16
    unsigned int u = __builtin_bit_cast(unsigned int, f);
    u += 0x7FFFu + ((u >> 16) & 1u);
    return (unsigned short)(u >> 16);
}
__device__ __forceinline__ float bf2f(unsigned short b) {
    unsigned int u = ((unsigned int)b) << 16;
    return __builtin_bit_cast(float, u);
}

// ---------------------------------------------------------------- init: zero padded counters, stats; cast-transpose W
__global__ __launch_bounds__(256) void k_init(int* __restrict__ cnt,
                                              float* __restrict__ sums,
                                              float* __restrict__ sumsq,
                                              const float* __restrict__ W,
                                              unsigned short* __restrict__ wt) {
    int i = blockIdx.x * 256 + threadIdx.x;
    if (i < N_NODES * PAD / 4) ((int4*)cnt)[i] = make_int4(0, 0, 0, 0);
    if (i < C) { sums[i] = 0.0f; sumsq[i] = 0.0f; }
    if (i < C * C) wt[i] = f2bf(W[(i & 127) * C + (i >> 7)]);   // wt[c][k] = W[k][c]
}

// ---------------------------------------------------------------- count + rank capture: 2 edges/thread
__global__ __launch_bounds__(256) void k_count(const int* __restrict__ dst,
                                               int* __restrict__ cnt,
                                               unsigned short* __restrict__ rank) {
    int e0 = (blockIdx.x * 256 + threadIdx.x) * 2;   // N_EDGES % 512 == 0
    int2 d = *(const int2*)&dst[e0];
    int r0 = atomicAdd(&cnt[d.x * PAD], 1);
    int r1 = atomicAdd(&cnt[d.y * PAD], 1);
    rank[e0]     = (unsigned short)r0;
    rank[e0 + 1] = (unsigned short)r1;
}

// ---------------------------------------------------------------- scan pass 1 (+ dinv = rsqrt(deg+1))
__global__ __launch_bounds__(256) void k_scan1(const int* __restrict__ cnt,
                                               int* __restrict__ offs,
                                               int* __restrict__ bsum,
                                               float* __restrict__ dinv) {
    __shared__ int tmp[256];
    int i = blockIdx.x * 256 + threadIdx.x;
    int v = (i < N_NODES) ? cnt[i * PAD] : 0;
    if (i < N_NODES) dinv[i] = rsqrtf((float)(v + 1));
    tmp[threadIdx.x] = v;
    __syncthreads();
    for (int off = 1; off < 256; off <<= 1) {
        int t = (threadIdx.x >= off) ? tmp[threadIdx.x - off] : 0;
        __syncthreads();
        tmp[threadIdx.x] += t;
        __syncthreads();
    }
    if (i < N_NODES) offs[i] = tmp[threadIdx.x] - v;
    if (threadIdx.x == 255) bsum[blockIdx.x] = tmp[255];
}

// ---------------------------------------------------------------- scan pass 2
__global__ __launch_bounds__(512) void k_scan2(int* __restrict__ bsum) {
    __shared__ int tmp[512];
    int v = (threadIdx.x < NB1) ? bsum[threadIdx.x] : 0;
    tmp[threadIdx.x] = v;
    __syncthreads();
    for (int off = 1; off < 512; off <<= 1) {
        int t = (threadIdx.x >= off) ? tmp[threadIdx.x - off] : 0;
        __syncthreads();
        tmp[threadIdx.x] += t;
        __syncthreads();
    }
    if (threadIdx.x < NB1) bsum[threadIdx.x] = tmp[threadIdx.x] - v;
}

// ---------------------------------------------------------------- scan pass 3 (+ sentinel)
__global__ __launch_bounds__(256) void k_scan3(int* __restrict__ offs,
                                               const int* __restrict__ bsum) {
    int i = blockIdx.x * 256 + threadIdx.x;
    if (i < N_NODES) offs[i] += bsum[blockIdx.x];
    if (i == 0) offs[N_NODES] = N_EDGES;
}

// ---------------------------------------------------------------- bucket fill: NO atomics (rank precomputed)
__global__ __launch_bounds__(256) void k_fill(const int* __restrict__ src,
                                              const int* __restrict__ dst,
                                              const int* __restrict__ offs,
                                              const unsigned short* __restrict__ rank,
                                              int* __restrict__ srt) {
    int e = blockIdx.x * 256 + threadIdx.x;   // N_EDGES % 256 == 0
    int d = dst[e];
    srt[offs[d] + (int)rank[e]] = src[e];
}

// ---------------------------------------------------------------- hs = (x @ W) * dinv[row], bf16 MFMA, fused cast
__global__ __launch_bounds__(256) void k_gemm(const float* __restrict__ x,
                                              const unsigned short* __restrict__ wt,
                                              const float* __restrict__ dinv,
                                              unsigned short* __restrict__ hs) {
    int tile = blockIdx.x * 4 + (threadIdx.x >> 6);
    if (tile >= N_NODES / 16) return;
    int lane = threadIdx.x & 63;
    int row0 = tile * 16;

    int ar = lane & 15;
    int kg = (lane >> 4) * 8;

    short8 a[4];
    #pragma unroll
    for (int kk = 0; kk < 4; ++kk) {
        const float* p = &x[(size_t)(row0 + ar) * C + kk * 32 + kg];
        float4 p0 = *(const float4*)p;
        float4 p1 = *(const float4*)(p + 4);
        short8 av;
        av[0] = (short)f2bf(p0.x); av[1] = (short)f2bf(p0.y);
        av[2] = (short)f2bf(p0.z); av[3] = (short)f2bf(p0.w);
        av[4] = (short)f2bf(p1.x); av[5] = (short)f2bf(p1.y);
        av[6] = (short)f2bf(p1.z); av[7] = (short)f2bf(p1.w);
        a[kk] = av;
    }

    int rb = (lane >> 4) * 4;
    float dv[4];
    #pragma unroll
    for (int r = 0; r < 4; ++r) dv[r] = dinv[row0 + rb + r];

    #pragma unroll
    for (int ct = 0; ct < 8; ++ct) {
        f32x4 acc = {0.f, 0.f, 0.f, 0.f};
        #pragma unroll
        for (int kk = 0; kk < 4; ++kk) {
            short8 b = *(const short8*)&wt[(size_t)(ct * 16 + ar) * C + kk * 32 + kg];
            acc = __builtin_amdgcn_mfma_f32_16x16x32_bf16(a[kk], b, acc, 0, 0, 0);
        }
        int col = ct * 16 + ar;
        #pragma unroll
        for (int r = 0; r < 4; ++r)
            hs[(size_t)(row0 + rb + r) * C + col] = f2bf(acc[r] * dv[r]);
    }
}

// ---------------------------------------------------------------- CSR aggregate: 32 lanes/node, 8-wide MLP gathers
__global__ __launch_bounds__(256) void k_aggregate(const ushort4* __restrict__ h4,
                                                   const int* __restrict__ srt,
                                                   const int* __restrict__ offs,
                                                   const float* __restrict__ dinv,
                                                   const float* __restrict__ bias,
                                                   float* __restrict__ out) {
    int node = blockIdx.x * 8 + (threadIdx.x >> 5);
    int lane = threadIdx.x & 31;

    float dn = dinv[node];
    int beg = offs[node];
    int end = offs[node + 1];

    ushort4 ms = h4[(size_t)node * 32 + lane];
    float ax = bf2f(ms.x), ay = bf2f(ms.y), az = bf2f(ms.z), aw = bf2f(ms.w);

    for (int k = beg; k < end; k += 8) {
        int   idx[8];
        float msk[8];
        #pragma unroll
        for (int i = 0; i < 8; ++i) {
            int ki = k + i;
            msk[i] = (ki < end) ? 1.0f : 0.0f;
            idx[i] = srt[(ki < end) ? ki : end - 1];
        }
        ushort4 m[8];
        #pragma unroll
        for (int i = 0; i < 8; ++i) m[i] = h4[(size_t)idx[i] * 32 + lane];
        #pragma unroll
        for (int i = 0; i < 8; ++i) {
            ax += msk[i] * bf2f(m[i].x);
            ay += msk[i] * bf2f(m[i].y);
            az += msk[i] * bf2f(m[i].z);
            aw += msk[i] * bf2f(m[i].w);
        }
    }

    float4 b = ((const float4*)bias)[lane];
    float4 v;
    v.x = dn * ax + b.x;
    v.y = dn * ay + b.y;
    v.z = dn * az + b.z;
    v.w = dn * aw + b.w;
    v.x = v.x > 0.f ? v.x : LEAKY * v.x;
    v.y = v.y > 0.f ? v.y : LEAKY * v.y;
    v.z = v.z > 0.f ? v.z : LEAKY * v.z;
    v.w = v.w > 0.f ? v.w : LEAKY * v.w;
    ((float4*)out)[(size_t)node * 32 + lane] = v;
}

// ---------------------------------------------------------------- BN stats
__global__ __launch_bounds__(256) void k_stats(const float* __restrict__ out,
                                               float* __restrict__ sums,
                                               float* __restrict__ sumsq) {
    int c = threadIdx.x & 127;
    int half = threadIdx.x >> 7;
    int base = blockIdx.x * 256;
    float s = 0.0f, q = 0.0f;
    for (int r = half; r < 256; r += 2) {
        int n = base + r;
        if (n >= N_NODES) break;
        float v = out[(size_t)n * C + c];
        s += v; q += v * v;
    }
    __shared__ float ls[256], lq[256];
    ls[threadIdx.x] = s; lq[threadIdx.x] = q;
    __syncthreads();
    if (threadIdx.x < 128) {
        atomicAdd(&sums[c],  ls[threadIdx.x] + ls[threadIdx.x + 128]);
        atomicAdd(&sumsq[c], lq[threadIdx.x] + lq[threadIdx.x + 128]);
    }
}

// ---------------------------------------------------------------- fold BN params
__global__ void k_params(const float* __restrict__ sums, const float* __restrict__ sumsq,
                         const float* __restrict__ gamma, const float* __restrict__ beta,
                         float* __restrict__ scale, float* __restrict__ shift) {
    int c = threadIdx.x;
    float inv_n = 1.0f / (float)N_NODES;
    float mean = sums[c] * inv_n;
    float var = sumsq[c] * inv_n - mean * mean;
    float sc = gamma[c] * rsqrtf(var + BN_EPS);
    scale[c] = sc;
    shift[c] = beta[c] - mean * sc;
}

// ---------------------------------------------------------------- apply
__global__ __launch_bounds__(256) void k_apply(float* __restrict__ out,
                                               const float* __restrict__ scale,
                                               const float* __restrict__ shift) {
    int i = blockIdx.x * 256 + threadIdx.x;
    int c4 = i & 31;
    float4 v = ((float4*)out)[i];
    float4 sc = ((const float4*)scale)[c4];
    float4 sh = ((const float4*)shift)[c4];
    v.x = v.x * sc.x + sh.x;
    v.y = v.y * sc.y + sh.y;
    v.z = v.z * sc.z + sh.z;
    v.w = v.w * sc.w + sh.w;
    ((float4*)out)[i] = v;
}

extern "C" void kernel_launch(void* const* d_in, const int* in_sizes, int n_in,
                              void* d_out, int out_size, void* d_ws, size_t ws_size,
                              hipStream_t stream) {
    const float* x     = (const float*)d_in[0];
    const int*   edge  = (const int*)d_in[1];
    const float* W     = (const float*)d_in[2];
    const float* bias  = (const float*)d_in[3];
    const float* gamma = (const float*)d_in[4];
    const float* beta  = (const float*)d_in[5];
    float* out = (float*)d_out;
    char* ws = (char*)d_ws;

    // workspace layout (~42.5 MB)
    unsigned short* hs   = (unsigned short*)ws;  ws += (size_t)N_NODES * C * 2;   // 25.6 MB
    unsigned short* wt   = (unsigned short*)ws;  ws += (size_t)C * C * 2;         // 32 KB
    unsigned short* rank = (unsigned short*)ws;  ws += (size_t)N_EDGES * 2;       // 3.2 MB
    int*   srt    = (int*)ws;                    ws += (size_t)N_EDGES * 4;       // 6.4 MB
    int*   cnt    = (int*)ws;                    ws += (size_t)N_NODES * PAD * 4; // 6.4 MB padded
    int*   offs   = (int*)ws;                    ws += (size_t)(N_NODES + 1) * 4;
    int*   bsum   = (int*)ws;                    ws += 512 * 4;
    float* dinv   = (float*)ws;                  ws += (size_t)N_NODES * 4;
    float* sums   = (float*)ws;                  ws += C * 4;
    float* sumsq  = (float*)ws;                  ws += C * 4;
    float* scale  = (float*)ws;                  ws += C * 4;
    float* shift  = (float*)ws;

    const int* src = edge;
    const int* dst = edge + N_EDGES;

    k_init     <<<(N_NODES * PAD / 4 + 255) / 256, 256, 0, stream>>>(cnt, sums, sumsq, W, wt);
    k_count    <<<N_EDGES / 512,         256, 0, stream>>>(dst, cnt, rank);
    k_scan1    <<<NB1,                   256, 0, stream>>>(cnt, offs, bsum, dinv);
    k_scan2    <<<1,                     512, 0, stream>>>(bsum);
    k_scan3    <<<NB1,                   256, 0, stream>>>(offs, bsum);
    k_fill     <<<N_EDGES / 256,         256, 0, stream>>>(src, dst, offs, rank, srt);
    k_gemm     <<<(N_NODES / 16 + 3) / 4, 256, 0, stream>>>(x, wt, dinv, hs);
    k_aggregate<<<N_NODES / 8,           256, 0, stream>>>((const ushort4*)hs, srt, offs, dinv, bias, out);
    k_stats    <<<NB1,                   256, 0, stream>>>(out, sums, sumsq);
    k_params   <<<1, 128,                     0, stream>>>(sums, sumsq, gamma, beta, scale, shift);
    k_apply    <<<N_NODES * C / 4 / 256, 256, 0, stream>>>(out, scale, shift);
}

// Round 7
// 217.332 us; speedup vs baseline: 1.7759x; 1.2289x over previous
//
#include <hip/hip_runtime.h>

#define N_NODES 100000
#define N_EDGES 1600000
#define C 128
#define LEAKY 0.01f
#define BN_EPS 1e-5f
#define NB1 391            // ceil(N_NODES/256)
#define NB_C 391           // coarse buckets (dst>>8), 256 nodes each
#define PB 391             // partition blocks
#define PBLK 4096          // edges per partition block
#define STASH 8192         // fine-kernel LDS pair stash (avg bucket = 4092)

typedef __attribute__((ext_vector_type(8))) short short8;   // 8 bf16 = 16B
typedef __attribute__((ext_vector_type(4))) float f32x4;

__device__ __forceinline__ unsigned short f2bf(float f) {   // RNE float->bf16
    unsigned int u = __builtin_bit_cast(unsigned int, f);
    u += 0x7FFFu + ((u >> 16) & 1u);
    return (unsigned short)(u >> 16);
}
__device__ __forceinline__ float bf2f(unsigned short b) {
    unsigned int u = ((unsigned int)b) << 16;
    return __builtin_bit_cast(float, u);
}

// ---------------------------------------------------------------- init: zero stats; cast-transpose W
__global__ __launch_bounds__(256) void k_init(float* __restrict__ sums,
                                              float* __restrict__ sumsq,
                                              const float* __restrict__ W,
                                              unsigned short* __restrict__ wt) {
    int i = blockIdx.x * 256 + threadIdx.x;
    if (i < C) { sums[i] = 0.0f; sumsq[i] = 0.0f; }
    if (i < C * C) wt[i] = f2bf(W[(i & 127) * C + (i >> 7)]);   // wt[c][k] = W[k][c]
}

// ---------------------------------------------------------------- coarse histogram: per-block counts per bucket
__global__ __launch_bounds__(256) void k_coarse(const int* __restrict__ dst,
                                                int* __restrict__ blk_cnt) {
    __shared__ int lh[NB_C];
    int tid = threadIdx.x, blk = blockIdx.x;
    for (int i = tid; i < NB_C; i += 256) lh[i] = 0;
    __syncthreads();
    #pragma unroll
    for (int it = 0; it < PBLK / 256; ++it) {
        int e = blk * PBLK + it * 256 + tid;
        if (e < N_EDGES) atomicAdd(&lh[dst[e] >> 8], 1);
    }
    __syncthreads();
    for (int i = tid; i < NB_C; i += 256) blk_cnt[i * PB + blk] = lh[i];
}

// ---------------------------------------------------------------- per-bucket exclusive scan over blocks
__global__ __launch_bounds__(512) void k_offsets(const int* __restrict__ blk_cnt,
                                                 int* __restrict__ offset,
                                                 int* __restrict__ total) {
    __shared__ int tmp[512];
    int t = threadIdx.x, k = blockIdx.x;
    int v = (t < PB) ? blk_cnt[k * PB + t] : 0;
    tmp[t] = v;
    __syncthreads();
    for (int off = 1; off < 512; off <<= 1) {
        int u = (t >= off) ? tmp[t - off] : 0;
        __syncthreads();
        tmp[t] += u;
        __syncthreads();
    }
    if (t < PB) offset[k * PB + t] = tmp[t] - v;
    if (t == 511) total[k] = tmp[511];
}

// ---------------------------------------------------------------- bucket-base scan (1 block)
__global__ __launch_bounds__(512) void k_cbase(const int* __restrict__ total,
                                               int* __restrict__ cbase,
                                               int* __restrict__ offs) {
    __shared__ int tmp[512];
    int t = threadIdx.x;
    int v = (t < NB_C) ? total[t] : 0;
    tmp[t] = v;
    __syncthreads();
    for (int off = 1; off < 512; off <<= 1) {
        int u = (t >= off) ? tmp[t - off] : 0;
        __syncthreads();
        tmp[t] += u;
        __syncthreads();
    }
    if (t < NB_C) cbase[t] = tmp[t] - v;
    if (t == 0) { cbase[NB_C] = N_EDGES; offs[N_NODES] = N_EDGES; }
}

// ---------------------------------------------------------------- partition: packed (src | dlow<<17) into bucket chunks
__global__ __launch_bounds__(256) void k_partition(const int* __restrict__ src,
                                                   const int* __restrict__ dst,
                                                   const int* __restrict__ cbase,
                                                   const int* __restrict__ offset,
                                                   unsigned int* __restrict__ pairs) {
    __shared__ int lh[NB_C];
    __shared__ int lbase[NB_C];
    int tid = threadIdx.x, blk = blockIdx.x;
    for (int i = tid; i < NB_C; i += 256) {
        lh[i] = 0;
        lbase[i] = cbase[i] + offset[i * PB + blk];
    }
    __syncthreads();
    #pragma unroll
    for (int it = 0; it < PBLK / 256; ++it) {
        int e = blk * PBLK + it * 256 + tid;
        if (e < N_EDGES) {
            int d = dst[e];
            int b = d >> 8;
            int r = atomicAdd(&lh[b], 1);
            pairs[lbase[b] + r] = (unsigned int)src[e] | ((unsigned int)(d & 255) << 17);
        }
    }
}

// ---------------------------------------------------------------- fine: per-bucket hist -> dinv+offs; LDS-rank -> srt
__global__ __launch_bounds__(256) void k_fine(const unsigned int* __restrict__ pairs,
                                              const int* __restrict__ cbase,
                                              float* __restrict__ dinv,
                                              int* __restrict__ offs,
                                              int* __restrict__ srt) {
    __shared__ int hist[256];
    __shared__ int loff[256];
    __shared__ int cnt2[256];
    __shared__ unsigned int stash[STASH];
    int tid = threadIdx.x, blk = blockIdx.x;
    int nbase = blk * 256;
    int nn = (nbase + 256 <= N_NODES) ? 256 : (N_NODES - nbase);
    int ebeg = cbase[blk];
    int ne = cbase[blk + 1] - ebeg;

    hist[tid] = 0; cnt2[tid] = 0;
    __syncthreads();
    for (int k = tid; k < ne; k += 256) {
        unsigned int pk = pairs[ebeg + k];
        if (k < STASH) stash[k] = pk;
        atomicAdd(&hist[pk >> 17], 1);
    }
    __syncthreads();
    if (tid < nn) dinv[nbase + tid] = rsqrtf((float)(hist[tid] + 1));
    // exclusive scan of hist into loff
    loff[tid] = hist[tid];
    __syncthreads();
    for (int off = 1; off < 256; off <<= 1) {
        int u = (tid >= off) ? loff[tid - off] : 0;
        __syncthreads();
        loff[tid] += u;
        __syncthreads();
    }
    loff[tid] -= hist[tid];           // exclusive
    if (tid < nn) offs[nbase + tid] = ebeg + loff[tid];
    __syncthreads();
    for (int k = tid; k < ne; k += 256) {
        unsigned int pk = (k < STASH) ? stash[k] : pairs[ebeg + k];
        int dl = pk >> 17;
        int r = atomicAdd(&cnt2[dl], 1);
        srt[ebeg + loff[dl] + r] = (int)(pk & 0x1FFFFu);
    }
}

// ---------------------------------------------------------------- hs = (x @ W) * dinv[row], bf16 MFMA, fused cast
__global__ __launch_bounds__(256) void k_gemm(const float* __restrict__ x,
                                              const unsigned short* __restrict__ wt,
                                              const float* __restrict__ dinv,
                                              unsigned short* __restrict__ hs) {
    int tile = blockIdx.x * 4 + (threadIdx.x >> 6);
    if (tile >= N_NODES / 16) return;
    int lane = threadIdx.x & 63;
    int row0 = tile * 16;

    int ar = lane & 15;
    int kg = (lane >> 4) * 8;

    short8 a[4];
    #pragma unroll
    for (int kk = 0; kk < 4; ++kk) {
        const float* p = &x[(size_t)(row0 + ar) * C + kk * 32 + kg];
        float4 p0 = *(const float4*)p;
        float4 p1 = *(const float4*)(p + 4);
        short8 av;
        av[0] = (short)f2bf(p0.x); av[1] = (short)f2bf(p0.y);
        av[2] = (short)f2bf(p0.z); av[3] = (short)f2bf(p0.w);
        av[4] = (short)f2bf(p1.x); av[5] = (short)f2bf(p1.y);
        av[6] = (short)f2bf(p1.z); av[7] = (short)f2bf(p1.w);
        a[kk] = av;
    }

    int rb = (lane >> 4) * 4;
    float dv[4];
    #pragma unroll
    for (int r = 0; r < 4; ++r) dv[r] = dinv[row0 + rb + r];

    #pragma unroll
    for (int ct = 0; ct < 8; ++ct) {
        f32x4 acc = {0.f, 0.f, 0.f, 0.f};
        #pragma unroll
        for (int kk = 0; kk < 4; ++kk) {
            short8 b = *(const short8*)&wt[(size_t)(ct * 16 + ar) * C + kk * 32 + kg];
            acc = __builtin_amdgcn_mfma_f32_16x16x32_bf16(a[kk], b, acc, 0, 0, 0);
        }
        int col = ct * 16 + ar;
        #pragma unroll
        for (int r = 0; r < 4; ++r)
            hs[(size_t)(row0 + rb + r) * C + col] = f2bf(acc[r] * dv[r]);
    }
}

// ---------------------------------------------------------------- CSR aggregate: 32 lanes/node, 8-wide MLP gathers
__global__ __launch_bounds__(256) void k_aggregate(const ushort4* __restrict__ h4,
                                                   const int* __restrict__ srt,
                                                   const int* __restrict__ offs,
                                                   const float* __restrict__ dinv,
                                                   const float* __restrict__ bias,
                                                   float* __restrict__ out) {
    int node = blockIdx.x * 8 + (threadIdx.x >> 5);
    int lane = threadIdx.x & 31;

    float dn = dinv[node];
    int beg = offs[node];
    int end = offs[node + 1];

    ushort4 ms = h4[(size_t)node * 32 + lane];
    float ax = bf2f(ms.x), ay = bf2f(ms.y), az = bf2f(ms.z), aw = bf2f(ms.w);

    for (int k = beg; k < end; k += 8) {
        int   idx[8];
        float msk[8];
        #pragma unroll
        for (int i = 0; i < 8; ++i) {
            int ki = k + i;
            msk[i] = (ki < end) ? 1.0f : 0.0f;
            idx[i] = srt[(ki < end) ? ki : end - 1];
        }
        ushort4 m[8];
        #pragma unroll
        for (int i = 0; i < 8; ++i) m[i] = h4[(size_t)idx[i] * 32 + lane];
        #pragma unroll
        for (int i = 0; i < 8; ++i) {
            ax += msk[i] * bf2f(m[i].x);
            ay += msk[i] * bf2f(m[i].y);
            az += msk[i] * bf2f(m[i].z);
            aw += msk[i] * bf2f(m[i].w);
        }
    }

    float4 b = ((const float4*)bias)[lane];
    float4 v;
    v.x = dn * ax + b.x;
    v.y = dn * ay + b.y;
    v.z = dn * az + b.z;
    v.w = dn * aw + b.w;
    v.x = v.x > 0.f ? v.x : LEAKY * v.x;
    v.y = v.y > 0.f ? v.y : LEAKY * v.y;
    v.z = v.z > 0.f ? v.z : LEAKY * v.z;
    v.w = v.w > 0.f ? v.w : LEAKY * v.w;
    ((float4*)out)[(size_t)node * 32 + lane] = v;
}

// ---------------------------------------------------------------- BN stats
__global__ __launch_bounds__(256) void k_stats(const float* __restrict__ out,
                                               float* __restrict__ sums,
                                               float* __restrict__ sumsq) {
    int c = threadIdx.x & 127;
    int half = threadIdx.x >> 7;
    int base = blockIdx.x * 256;
    float s = 0.0f, q = 0.0f;
    for (int r = half; r < 256; r += 2) {
        int n = base + r;
        if (n >= N_NODES) break;
        float v = out[(size_t)n * C + c];
        s += v; q += v * v;
    }
    __shared__ float ls[256], lq[256];
    ls[threadIdx.x] = s; lq[threadIdx.x] = q;
    __syncthreads();
    if (threadIdx.x < 128) {
        atomicAdd(&sums[c],  ls[threadIdx.x] + ls[threadIdx.x + 128]);
        atomicAdd(&sumsq[c], lq[threadIdx.x] + lq[threadIdx.x + 128]);
    }
}

// ---------------------------------------------------------------- fold BN params
__global__ void k_params(const float* __restrict__ sums, const float* __restrict__ sumsq,
                         const float* __restrict__ gamma, const float* __restrict__ beta,
                         float* __restrict__ scale, float* __restrict__ shift) {
    int c = threadIdx.x;
    float inv_n = 1.0f / (float)N_NODES;
    float mean = sums[c] * inv_n;
    float var = sumsq[c] * inv_n - mean * mean;
    float sc = gamma[c] * rsqrtf(var + BN_EPS);
    scale[c] = sc;
    shift[c] = beta[c] - mean * sc;
}

// ---------------------------------------------------------------- apply
__global__ __launch_bounds__(256) void k_apply(float* __restrict__ out,
                                               const float* __restrict__ scale,
                                               const float* __restrict__ shift) {
    int i = blockIdx.x * 256 + threadIdx.x;
    int c4 = i & 31;
    float4 v = ((float4*)out)[i];
    float4 sc = ((const float4*)scale)[c4];
    float4 sh = ((const float4*)shift)[c4];
    v.x = v.x * sc.x + sh.x;
    v.y = v.y * sc.y + sh.y;
    v.z = v.z * sc.z + sh.z;
    v.w = v.w * sc.w + sh.w;
    ((float4*)out)[i] = v;
}

extern "C" void kernel_launch(void* const* d_in, const int* in_sizes, int n_in,
                              void* d_out, int out_size, void* d_ws, size_t ws_size,
                              hipStream_t stream) {
    const float* x     = (const float*)d_in[0];
    const int*   edge  = (const int*)d_in[1];
    const float* W     = (const float*)d_in[2];
    const float* bias  = (const float*)d_in[3];
    const float* gamma = (const float*)d_in[4];
    const float* beta  = (const float*)d_in[5];
    float* out = (float*)d_out;
    char* ws = (char*)d_ws;

    // workspace layout (~41 MB)
    unsigned short* hs    = (unsigned short*)ws;  ws += (size_t)N_NODES * C * 2;   // 25.6 MB
    unsigned short* wt    = (unsigned short*)ws;  ws += (size_t)C * C * 2;         // 32 KB
    unsigned int*   pairs = (unsigned int*)ws;    ws += (size_t)N_EDGES * 4;       // 6.4 MB
    int*   srt     = (int*)ws;                    ws += (size_t)N_EDGES * 4;       // 6.4 MB
    int*   blk_cnt = (int*)ws;                    ws += (size_t)NB_C * PB * 4;     // 612 KB
    int*   offset  = (int*)ws;                    ws += (size_t)NB_C * PB * 4;     // 612 KB
    int*   total   = (int*)ws;                    ws += 512 * 4;
    int*   cbase   = (int*)ws;                    ws += 512 * 4;
    int*   offs    = (int*)ws;                    ws += (size_t)(N_NODES + 1) * 4;
    float* dinv    = (float*)ws;                  ws += (size_t)N_NODES * 4;
    float* sums    = (float*)ws;                  ws += C * 4;
    float* sumsq   = (float*)ws;                  ws += C * 4;
    float* scale   = (float*)ws;                  ws += C * 4;
    float* shift   = (float*)ws;

    const int* src = edge;
    const int* dst = edge + N_EDGES;

    k_init     <<<C * C / 256,           256, 0, stream>>>(sums, sumsq, W, wt);
    k_coarse   <<<PB,                    256, 0, stream>>>(dst, blk_cnt);
    k_offsets  <<<NB_C,                  512, 0, stream>>>(blk_cnt, offset, total);
    k_cbase    <<<1,                     512, 0, stream>>>(total, cbase, offs);
    k_partition<<<PB,                    256, 0, stream>>>(src, dst, cbase, offset, pairs);
    k_fine     <<<NB_C,                  256, 0, stream>>>(pairs, cbase, dinv, offs, srt);
    k_gemm     <<<(N_NODES / 16 + 3) / 4, 256, 0, stream>>>(x, wt, dinv, hs);
    k_aggregate<<<N_NODES / 8,           256, 0, stream>>>((const ushort4*)hs, srt, offs, dinv, bias, out);
    k_stats    <<<NB1,                   256, 0, stream>>>(out, sums, sumsq);
    k_params   <<<1, 128,                     0, stream>>>(sums, sumsq, gamma, beta, scale, shift);
    k_apply    <<<N_NODES * C / 4 / 256, 256, 0, stream>>>(out, scale, shift);
}